// Round 20
// baseline (898.143 us; speedup 1.0000x reference)
//
#include <hip/hip_runtime.h>
#include <cstdint>
#include <cstddef>

typedef __attribute__((ext_vector_type(4))) float f32x4;
typedef __attribute__((ext_vector_type(8))) short s16x8;
typedef __attribute__((ext_vector_type(4))) short s16x4;

__device__ __forceinline__ short f2bf(float f){
  unsigned u; __builtin_memcpy(&u, &f, 4);
  u += 0x7fffu + ((u >> 16) & 1u);
  return (short)(u >> 16);
}
__device__ __forceinline__ float bf2f(short s){
  unsigned u = ((unsigned)(unsigned short)s) << 16;
  float f; __builtin_memcpy(&f, &u, 4);
  return f;
}

__device__ __forceinline__ void gll16(const void* g, void* l) {
  auto* lp = (__attribute__((address_space(3))) unsigned*)(uintptr_t)(l);
  const auto* gp = (const __attribute__((address_space(1))) unsigned*)(uintptr_t)(g);
  __builtin_amdgcn_global_load_lds(gp, lp, 16, 0, 0);
}

__device__ __forceinline__ void ds_tr8(unsigned a, s16x4* r) {
  asm volatile(
    "ds_read_b64_tr_b16 %0, %8\n\t"
    "ds_read_b64_tr_b16 %1, %8 offset:512\n\t"
    "ds_read_b64_tr_b16 %2, %8 offset:2048\n\t"
    "ds_read_b64_tr_b16 %3, %8 offset:2560\n\t"
    "ds_read_b64_tr_b16 %4, %8 offset:4096\n\t"
    "ds_read_b64_tr_b16 %5, %8 offset:4608\n\t"
    "ds_read_b64_tr_b16 %6, %8 offset:6144\n\t"
    "ds_read_b64_tr_b16 %7, %8 offset:6656\n\t"
    "s_waitcnt lgkmcnt(0)"
    : "=&v"(r[0]), "=&v"(r[1]), "=&v"(r[2]), "=&v"(r[3]),
      "=&v"(r[4]), "=&v"(r[5]), "=&v"(r[6]), "=&v"(r[7])
    : "v"(a)
    : "memory");
}

// fragment-major packed index, ntk = K/32
__device__ __forceinline__ int pidx(int m, int k, int ntk) {
  return ((m >> 4) * ntk + (k >> 5)) * 512 + ((((k >> 3) & 3) * 16 + (m & 15)) << 3) + (k & 7);
}

// ---------------- encode: -> bf16 resid ----------------
__global__ __launch_bounds__(256) void encode_kernel(
    const float* __restrict__ x, const float* __restrict__ W,
    const float* __restrict__ b, short* __restrict__ out)
{
  const int t = blockIdx.x;
  float xv[8];
#pragma unroll
  for (int f = 0; f < 8; ++f) xv[f] = x[(size_t)t*8 + f];
  for (int d = threadIdx.x; d < 512; d += 256) {
    float acc = b[d];
#pragma unroll
    for (int f = 0; f < 8; ++f) acc += xv[f] * W[f*512 + d];
    out[(size_t)t*512 + d] = f2bf(acc);
  }
}

// ---------------- LayerNorm: bf16 in -> bf16 row-major out ----------------
__global__ __launch_bounds__(256) void ln_kernel(
    const short* __restrict__ x16, short* __restrict__ out)
{
  const int w = threadIdx.x >> 6, lane = threadIdx.x & 63;
  const int t = blockIdx.x * 4 + w;
  s16x8 v = *(const s16x8*)&x16[(size_t)t*512 + lane*8];
  float vals[8];
#pragma unroll
  for (int i = 0; i < 8; ++i) vals[i] = bf2f(v[i]);
  float s = 0.f, sq = 0.f;
#pragma unroll
  for (int i = 0; i < 8; ++i) { s += vals[i]; sq += vals[i]*vals[i]; }
#pragma unroll
  for (int m = 1; m < 64; m <<= 1) { s += __shfl_xor(s, m); sq += __shfl_xor(sq, m); }
  float mean = s * (1.f/512.f);
  float var  = sq * (1.f/512.f) - mean*mean;
  float rstd = rsqrtf(var + 1e-5f);
  s16x8 o;
#pragma unroll
  for (int i = 0; i < 8; ++i) o[i] = f2bf((vals[i]-mean)*rstd);
  *(s16x8*)&out[(size_t)t*512 + lane*8] = o;
}

// ---------------- weight prep: all packed fragment-major ----------------
__global__ __launch_bounds__(256) void packB_kernel(
    const float* __restrict__ in, short* __restrict__ out, int K, int N)
{
  const int n = blockIdx.x * 256 + threadIdx.x;
  const int k = blockIdx.y;
  out[pidx(n, k, K >> 5)] = f2bf(in[(size_t)k * N + n]);
}

// source [N,K] row-major (centers)
__global__ __launch_bounds__(256) void packBNK_kernel(
    const float* __restrict__ in, short* __restrict__ out, int K, int N)
{
  const int k = blockIdx.x * 256 + threadIdx.x;
  const int n = blockIdx.y;
  out[pidx(n, k, K >> 5)] = f2bf(in[(size_t)n * K + k]);
}

// ====== GEMM A: 256x256 (qkv, W1), row-major A staged, packed-B regs ======
template<bool BIAS, bool RELU>
__global__ __launch_bounds__(512, 1) void gemm_regb_kernel(
    const short* __restrict__ A, const short* __restrict__ Bp,
    short* __restrict__ Cout, const float* __restrict__ bias, int M, int N, int K)
{
  __shared__ short As[4][256 * 32];   // 64 KB
  const int tid = threadIdx.x;
  const int lane = tid & 63, w = tid >> 6;
  const int wr = w >> 2, wc = w & 3;
  const int q = lane & 15, g = lane >> 4;

  const int nx = gridDim.x;
  const int d = blockIdx.y * nx + blockIdx.x;
  const int per = (nx * gridDim.y) >> 3;
  const int lid = (d & 7) * per + (d >> 3);
  const int bx = lid % nx, by = lid / nx;
  const int m0 = by * 256, n0 = bx * 256;

  const int srow = lane >> 2;
  const int scol = (((lane & 3) ^ ((lane >> 4) & 3)) * 8);
  const short* aS0 = A + (size_t)(m0 + w*32 + srow) * K + scol;
  const short* aS1 = aS0 + (size_t)16 * K;
  const int d0 = (w*2) * 512, d1 = (w*2 + 1) * 512;
  const int gs = (g ^ (q >> 2)) * 8;

  const int nt = K >> 5;
  const size_t bstep = (size_t)nt * 512;
  const short* bp0 = Bp + ((size_t)(n0 >> 4) + wc * 4) * bstep + lane * 8;

  f32x4 acc[8][4] = {};

  auto STAGE_A = [&](int tt) {
    const int k0 = tt << 5, nb = tt & 3;
    gll16(aS0 + k0, &As[nb][d0]);
    gll16(aS1 + k0, &As[nb][d1]);
  };
  s16x8 bA[4], bB[4];
  auto LOADB = [&](int tt, s16x8* bf) {
#pragma unroll
    for (int i = 0; i < 4; ++i)
      bf[i] = *(const s16x8*)&bp0[(size_t)i * bstep + (size_t)tt * 512];
  };
  auto TILE = [&](int t, s16x8* bcur, s16x8* bnxt, bool doLB, bool doSA) {
    __builtin_amdgcn_s_barrier();
    __builtin_amdgcn_sched_barrier(0);
    if (doLB) LOADB(t + 1, bnxt);
    __builtin_amdgcn_sched_barrier(0);
    if (doSA) STAGE_A(t + 3);
    __builtin_amdgcn_sched_barrier(0);
    const short* Ab = &As[t & 3][0];
    s16x8 aF[8];
#pragma unroll
    for (int i = 0; i < 8; ++i) aF[i] = *(const s16x8*)&Ab[(wr*128 + i*16 + q)*32 + gs];
    __builtin_amdgcn_s_setprio(1);
#pragma unroll
    for (int mi = 0; mi < 8; ++mi)
#pragma unroll
      for (int ni = 0; ni < 4; ++ni)
        acc[mi][ni] = __builtin_amdgcn_mfma_f32_16x16x32_bf16(aF[mi], bcur[ni], acc[mi][ni], 0, 0, 0);
    __builtin_amdgcn_s_setprio(0);
  };

  STAGE_A(0);
  LOADB(0, bA);
  STAGE_A(1);
  STAGE_A(2);

  for (int t = 0; t < nt - 2; t += 2) {
    asm volatile("s_waitcnt vmcnt(8)" ::: "memory");
    TILE(t, bA, bB, true, true);
    asm volatile("s_waitcnt vmcnt(8)" ::: "memory");
    TILE(t + 1, bB, bA, true, t + 4 < nt);
  }
  asm volatile("s_waitcnt vmcnt(6)" ::: "memory");
  TILE(nt - 2, bA, bB, true, false);
  asm volatile("s_waitcnt vmcnt(4)" ::: "memory");
  TILE(nt - 1, bB, bA, false, false);

#pragma unroll
  for (int mi = 0; mi < 8; ++mi) {
#pragma unroll
    for (int r = 0; r < 4; ++r) {
      const int gr = m0 + wr*128 + mi*16 + g*4 + r;
#pragma unroll
      for (int ni = 0; ni < 4; ++ni) {
        const int gc = n0 + wc*64 + ni*16 + q;
        float v = acc[mi][ni][r];
        if (BIAS) v += bias[gc];
        if (RELU) v = fmaxf(v, 0.f);
        Cout[(size_t)gr * N + gc] = f2bf(v);
      }
    }
  }
}

// ====== GEMM B: 128x256 (Wo, W2, cdist), 2 blocks/CU target ======
// 512 thr / 8 waves (2Mx4N), wave tile 64x64, acc[4][4]; A-LDS 32KB 4-buf,
// ONE gll16/thread/tile; packed-B register loads, ping-pong prefetch.
// vmcnt ledger (A=1,B=4 per iter; prologue A0,B0x4,A1,A2): steady vmcnt(6)
// [newest 6 = A(t+2),B(t)x4,A(t+1) => A(t) retired], tail 5/4.
// OUTMODE: 0 = bf16 rm (+resid16), 3 = FINAL (fp32 out + bf16 obf), 4 = cdist-argmin
template<bool BIAS, bool RESID16, int OUTMODE>
__global__ __launch_bounds__(512, 2) void gemm128_kernel(
    const short* __restrict__ A, const short* __restrict__ Bp,
    void* Cout, const float* __restrict__ bias,
    const short* __restrict__ resid16, short* __restrict__ obf,
    const float* __restrict__ cn2g, float* __restrict__ pminv,
    int* __restrict__ pmini, int M, int N, int K)
{
  __shared__ short As[4][128 * 32];   // 32 KB
  const int tid = threadIdx.x;
  const int lane = tid & 63, w = tid >> 6;
  const int wr = w >> 2, wc = w & 3;   // 2M x 4N
  const int q = lane & 15, g = lane >> 4;

  const int nx = gridDim.x;
  const int d = blockIdx.y * nx + blockIdx.x;
  const int per = (nx * gridDim.y) >> 3;
  const int lid = (d & 7) * per + (d >> 3);
  const int bx = lid % nx, by = lid / nx;
  const int m0 = by * 128, n0 = bx * 256;

  // A staging: thread covers (row = tid>>2, phys slot = tid&3); src col
  // pre-swizzled so phys p holds logical p^(row&3).
  const int srow = tid >> 2;
  const int scol = (((tid & 3) ^ (srow & 3)) * 8);
  const short* aS = A + (size_t)(m0 + srow) * K + scol;
  // fragment read: row r = wr*64+i*16+q (r&3 == q&3); logical g at phys g^(q&3)
  const int gs = (g ^ (q & 3)) * 8;

  const int nt = K >> 5;
  const size_t bstep = (size_t)nt * 512;
  const short* bp0 = Bp + ((size_t)(n0 >> 4) + wc * 4) * bstep + lane * 8;

  f32x4 acc[4][4] = {};

  auto STAGE_A = [&](int tt) {
    gll16(aS + (tt << 5), &As[tt & 3][tid * 8]);
  };
  s16x8 bA[4], bB[4];
  auto LOADB = [&](int tt, s16x8* bf) {
#pragma unroll
    for (int i = 0; i < 4; ++i)
      bf[i] = *(const s16x8*)&bp0[(size_t)i * bstep + (size_t)tt * 512];
  };
  auto TILE = [&](int t, s16x8* bcur, s16x8* bnxt, bool doLB, bool doSA) {
    __builtin_amdgcn_s_barrier();
    __builtin_amdgcn_sched_barrier(0);
    if (doLB) LOADB(t + 1, bnxt);
    __builtin_amdgcn_sched_barrier(0);
    if (doSA) STAGE_A(t + 3);
    __builtin_amdgcn_sched_barrier(0);
    const short* Ab = &As[t & 3][0];
    s16x8 aF[4];
#pragma unroll
    for (int i = 0; i < 4; ++i) aF[i] = *(const s16x8*)&Ab[(wr*64 + i*16 + q)*32 + gs];
    __builtin_amdgcn_s_setprio(1);
#pragma unroll
    for (int mi = 0; mi < 4; ++mi)
#pragma unroll
      for (int ni = 0; ni < 4; ++ni)
        acc[mi][ni] = __builtin_amdgcn_mfma_f32_16x16x32_bf16(aF[mi], bcur[ni], acc[mi][ni], 0, 0, 0);
    __builtin_amdgcn_s_setprio(0);
  };

  // prologue: A0(1), B0(4), A1(1), A2(1)
  STAGE_A(0);
  LOADB(0, bA);
  STAGE_A(1);
  STAGE_A(2);

  for (int t = 0; t < nt - 2; t += 2) {
    asm volatile("s_waitcnt vmcnt(6)" ::: "memory");
    TILE(t, bA, bB, true, true);              // stages A(t+3) <= A(nt-1)
    asm volatile("s_waitcnt vmcnt(6)" ::: "memory");
    TILE(t + 1, bB, bA, true, t + 4 < nt);
  }
  asm volatile("s_waitcnt vmcnt(5)" ::: "memory");
  TILE(nt - 2, bA, bB, true, false);
  asm volatile("s_waitcnt vmcnt(4)" ::: "memory");
  TILE(nt - 1, bB, bA, false, false);

  if (OUTMODE == 4) {
    float c2[4];
#pragma unroll
    for (int ni = 0; ni < 4; ++ni) c2[ni] = cn2g[n0 + wc*64 + ni*16 + q];
    float* redv = (float*)&As[0][0];   // 128*4 floats = 2 KB
    int*   redi = (int*)&As[1][0];
    __builtin_amdgcn_s_barrier();
#pragma unroll
    for (int mi = 0; mi < 4; ++mi) {
#pragma unroll
      for (int r = 0; r < 4; ++r) {
        float bv = 1e30f; int bidx = 0;
#pragma unroll
        for (int ni = 0; ni < 4; ++ni) {
          const int ci = n0 + wc*64 + ni*16 + q;
          const float dv = c2[ni] - 2.f * acc[mi][ni][r];
          if (dv < bv || (dv == bv && ci < bidx)) { bv = dv; bidx = ci; }
        }
#pragma unroll
        for (int mm = 1; mm < 16; mm <<= 1) {
          const float ov = __shfl_xor(bv, mm); const int oi = __shfl_xor(bidx, mm);
          if (ov < bv || (ov == bv && oi < bidx)) { bv = ov; bidx = oi; }
        }
        if (q == 0) {
          const int lr = wr*64 + mi*16 + g*4 + r;   // 0..127
          redv[lr*4 + wc] = bv; redi[lr*4 + wc] = bidx;
        }
      }
    }
    __syncthreads();
    if (tid < 128) {
      float bv = 1e30f; int bidx = 0;
#pragma unroll
      for (int j = 0; j < 4; ++j) {
        const float ov = redv[tid*4 + j]; const int oi = redi[tid*4 + j];
        if (ov < bv || (ov == bv && oi < bidx)) { bv = ov; bidx = oi; }
      }
      pminv[(size_t)(m0 + tid)*2 + bx] = bv;
      pmini[(size_t)(m0 + tid)*2 + bx] = bidx;
    }
  } else {
#pragma unroll
    for (int mi = 0; mi < 4; ++mi) {
#pragma unroll
      for (int r = 0; r < 4; ++r) {
        const int gr = m0 + wr*64 + mi*16 + g*4 + r;
#pragma unroll
        for (int ni = 0; ni < 4; ++ni) {
          const int gc = n0 + wc*64 + ni*16 + q;
          float v = acc[mi][ni][r];
          if (BIAS) v += bias[gc];
          const size_t idx = (size_t)gr * N + gc;
          if (RESID16) v += bf2f(resid16[idx]);
          if (OUTMODE == 0) ((short*)Cout)[idx] = f2bf(v);
          else { ((float*)Cout)[idx] = v; obf[idx] = f2bf(v); }
        }
      }
    }
  }
}

// ---------------- flash attention (unchanged) ----------------
__global__ __launch_bounds__(256) void attn_kernel(
    const short* __restrict__ qkv, short* __restrict__ attn_out)
{
  __shared__ short Ks[2][64 * 64];
  __shared__ short Vs[2][64 * 64];
  const int tid = threadIdx.x;
  const int w = tid >> 6, lane = tid & 63;
  const int q16 = lane & 15, g = lane >> 4;
  const int dd = blockIdx.x;
  const int lid = (dd & 7) * (int)(gridDim.x >> 3) + (dd >> 3);
  const int qt4 = lid & 7, h = (lid >> 3) & 7, b = lid >> 6;
  const size_t base = (size_t)b * 512 * 1536;
  const int qrow = qt4*64 + w*16 + q16;

  s16x8 bQ0, bQ1;
  {
    const size_t p = base + (size_t)qrow * 1536 + h*64 + g*8;
    bQ0 = *(const s16x8*)&qkv[p];
    bQ1 = *(const s16x8*)&qkv[p + 32];
  }

  const int c0 = w*2, c1 = w*2 + 1;
  const short* kS0 = qkv + base + (size_t)(c0*8 + (lane>>3))*1536 + 512 + h*64 + ((lane&7)^(lane>>3))*8;
  const short* kS1 = qkv + base + (size_t)(c1*8 + (lane>>3))*1536 + 512 + h*64 + ((lane&7)^(lane>>3))*8;
  const short* vS0 = qkv + base + (size_t)((c0&1)*32 + (lane>>1))*1536 + 1024 + h*64 + (c0>>1)*16 + (lane&1)*8;
  const short* vS1 = qkv + base + (size_t)((c1&1)*32 + (lane>>1))*1536 + 1024 + h*64 + (c1>>1)*16 + (lane&1)*8;

  const unsigned vs_lane = (unsigned)(size_t)(&Vs[0][0]) + (unsigned)((q16 + g*64)*2);
  const int sw = q16 & 7;

  float mrun = -1e30f, ssum = 0.f;
  f32x4 O[4] = {};

  gll16(kS0, &Ks[0][c0*512]);
  gll16(kS1, &Ks[0][c1*512]);
  gll16(vS0, &Vs[0][c0*512]);
  gll16(vS1, &Vs[0][c1*512]);
  __syncthreads();

  int cur = 0;
  for (int j0 = 0; j0 < 512; j0 += 64) {
    s16x8 ka0[4], ka1[4];
#pragma unroll
    for (int grp = 0; grp < 4; ++grp) {
      const int rb = (grp*16 + q16) * 64;
      ka0[grp] = *(const s16x8*)&Ks[cur][rb + ((g    ) ^ sw)*8];
      ka1[grp] = *(const s16x8*)&Ks[cur][rb + ((g + 4) ^ sw)*8];
    }
    if (j0 + 64 < 512) {
      const size_t joff = (size_t)(j0 + 64) * 1536;
      const int nxt = cur ^ 1;
      gll16(kS0 + joff, &Ks[nxt][c0*512]);
      gll16(kS1 + joff, &Ks[nxt][c1*512]);
      gll16(vS0 + joff, &Vs[nxt][c0*512]);
      gll16(vS1 + joff, &Vs[nxt][c1*512]);
    }
    __builtin_amdgcn_sched_barrier(0);

    f32x4 c[4];
    __builtin_amdgcn_s_setprio(1);
#pragma unroll
    for (int grp = 0; grp < 4; ++grp) {
      f32x4 z = {};
      c[grp] = __builtin_amdgcn_mfma_f32_16x16x32_bf16(ka0[grp], bQ0, z, 0, 0, 0);
      c[grp] = __builtin_amdgcn_mfma_f32_16x16x32_bf16(ka1[grp], bQ1, c[grp], 0, 0, 0);
    }
    __builtin_amdgcn_s_setprio(0);

    float sc[16];
#pragma unroll
    for (int grp = 0; grp < 4; ++grp)
#pragma unroll
      for (int r = 0; r < 4; ++r) sc[grp*4 + r] = c[grp][r] * 0.125f;
    float bm = sc[0];
#pragma unroll
    for (int i = 1; i < 16; ++i) bm = fmaxf(bm, sc[i]);
    bm = fmaxf(bm, __shfl_xor(bm, 16));
    bm = fmaxf(bm, __shfl_xor(bm, 32));
    const float mn = fmaxf(mrun, bm);
    const float alpha = __expf(mrun - mn);
    float p[16]; float bs = 0.f;
#pragma unroll
    for (int i = 0; i < 16; ++i) { p[i] = __expf(sc[i] - mn); bs += p[i]; }
    bs += __shfl_xor(bs, 16);
    bs += __shfl_xor(bs, 32);
    ssum = ssum * alpha + bs;
    mrun = mn;
#pragma unroll
    for (int db = 0; db < 4; ++db) O[db] *= alpha;

#pragma unroll
    for (int kk = 0; kk < 2; ++kk) {
      s16x8 pf;
#pragma unroll
      for (int e = 0; e < 8; ++e) pf[e] = f2bf(p[(kk*2 + (e >> 2))*4 + (e & 3)]);
      s16x4 r[8];
      ds_tr8(vs_lane + (unsigned)(cur << 13) + (unsigned)(kk*1024), r);
      __builtin_amdgcn_sched_barrier(0);
      __builtin_amdgcn_s_setprio(1);
#pragma unroll
      for (int db = 0; db < 4; ++db) {
        s16x8 vf = __builtin_shufflevector(r[2*db], r[2*db + 1], 0, 1, 2, 3, 4, 5, 6, 7);
        O[db] = __builtin_amdgcn_mfma_f32_16x16x32_bf16(vf, pf, O[db], 0, 0, 0);
      }
      __builtin_amdgcn_s_setprio(0);
    }
    __syncthreads();
    cur ^= 1;
  }

  const float inv = 1.f / ssum;
  const size_t tok = (size_t)b*512 + qrow;
#pragma unroll
  for (int db = 0; db < 4; ++db) {
    s16x4 ov;
#pragma unroll
    for (int r = 0; r < 4; ++r) ov[r] = f2bf(O[db][r] * inv);
    *(s16x4*)&attn_out[tok*512 + h*64 + db*16 + g*4] = ov;
  }
}

// ---------------- cn2 ----------------
__global__ __launch_bounds__(256) void cn2_kernel(
    const float* __restrict__ centers, float* __restrict__ cn2)
{
  const int c = blockIdx.x;
  __shared__ float red[256];
  float s = 0.f;
  for (int d = threadIdx.x; d < 512; d += 256) { float v = centers[(size_t)c*512 + d]; s += v*v; }
  red[threadIdx.x] = s; __syncthreads();
  for (int off = 128; off > 0; off >>= 1) {
    if (threadIdx.x < off) red[threadIdx.x] += red[threadIdx.x + off];
    __syncthreads();
  }
  if (threadIdx.x == 0) cn2[c] = red[0];
}

// ---------------- winner pick + loss partials ----------------
__global__ __launch_bounds__(256) void argmin_kernel(
    const float* __restrict__ pminv, const int* __restrict__ pmini,
    const float* __restrict__ seq, const float* __restrict__ centers,
    float* __restrict__ partial)
{
  const int w = threadIdx.x >> 6, lane = threadIdx.x & 63;
  const int t = blockIdx.x * 4 + w;
  const float d0 = pminv[(size_t)t*2], d1 = pminv[(size_t)t*2 + 1];
  const int   i0 = pmini[(size_t)t*2], i1 = pmini[(size_t)t*2 + 1];
  const int bi = (d1 < d0) ? i1 : i0;
  float s = 0.f;
#pragma unroll
  for (int j = 0; j < 8; ++j) {
    const int dcol = j*64 + lane;
    const float o = seq[(size_t)t*512 + dcol];
    const float c = centers[(size_t)bi*512 + dcol];
    const float dv = o - c;
    s += dv * dv;
  }
#pragma unroll
  for (int mm = 1; mm < 64; mm <<= 1) s += __shfl_xor(s, mm);
  __shared__ float red[4];
  if (lane == 0) red[w] = s;
  __syncthreads();
  if (threadIdx.x == 0) partial[blockIdx.x] = red[0] + red[1] + red[2] + red[3];
}

__global__ __launch_bounds__(256) void loss_kernel(
    const float* __restrict__ partial, int n, float* __restrict__ out)
{
  float s = 0.f;
  for (int i = threadIdx.x; i < n; i += 256) s += partial[i];
  __shared__ float red[256];
  red[threadIdx.x] = s; __syncthreads();
  for (int off = 128; off > 0; off >>= 1) {
    if (threadIdx.x < off) red[threadIdx.x] += red[threadIdx.x + off];
    __syncthreads();
  }
  if (threadIdx.x == 0) out[0] = red[0] * (1.f / 32768.f);
}

// ==========================================================================
extern "C" void kernel_launch(void* const* d_in, const int* in_sizes, int n_in,
                              void* d_out, int out_size, void* d_ws, size_t ws_size,
                              hipStream_t stream) {
  const float* x     = (const float*)d_in[0];
  const float* enc_W = (const float*)d_in[1];
  const float* enc_b = (const float*)d_in[2];
  const float* Wqkv  = (const float*)d_in[3];
  const float* Wo    = (const float*)d_in[4];
  const float* W1    = (const float*)d_in[5];
  const float* b1    = (const float*)d_in[6];
  const float* W2    = (const float*)d_in[7];
  const float* b2    = (const float*)d_in[8];
  const float* cen   = (const float*)d_in[9];
  float* out = (float*)d_out;

  const int NT = 32768;           // B*S tokens
  char* ws = (char*)d_ws;
  short* resid16 = (short*)(ws);                                  // 32 MB bf16 resid
  short* h_ln    = (short*)(ws + 67108864);                       // 32 MB row-major
  char*  pool    = ws + 100663296;                                // 128 MB shared pool
  short* qkv     = (short*)pool;                                  // 96 MB row-major
  short* attn_o  = (short*)(pool + 100663296);                    // 32 MB row-major
  short* hidden  = (short*)pool;                                  // 128 MB row-major (after attn)
  float* pminv   = (float*)pool;                                  // 256 KB (after hidden dead)
  int*   pmini   = (int*)(pool + 262144);                         // 256 KB
  short* wbase   = (short*)(ws + 234881024);                      // packed weights
  short* wqP     = wbase;                                         // 2 x 786432
  short* woP     = wbase + 1572864;                                // 2 x 262144
  short* w1P     = wbase + 2097152;                                // 2 x 1048576
  short* w2P     = wbase + 4194304;                                // 2 x 1048576
  short* cenP    = wbase + 6291456;                                // 262144
  float* cn2     = (float*)(ws + 247988224);
  float* partial = (float*)(ws + 247990272);

  // ---- weight prep: all packed ----
  for (int l = 0; l < 2; ++l) {
    packB_kernel<<<dim3(6, 512), 256, 0, stream>>>(Wqkv + (size_t)l*512*1536, wqP + (size_t)l*786432, 512, 1536);
    packB_kernel<<<dim3(2, 512), 256, 0, stream>>>(Wo   + (size_t)l*512*512,  woP + (size_t)l*262144, 512, 512);
    packB_kernel<<<dim3(8, 512), 256, 0, stream>>>(W1   + (size_t)l*512*2048, w1P + (size_t)l*1048576, 512, 2048);
    packB_kernel<<<dim3(2, 2048), 256, 0, stream>>>(W2  + (size_t)l*2048*512, w2P + (size_t)l*1048576, 2048, 512);
  }
  packBNK_kernel<<<dim3(2, 512), 256, 0, stream>>>(cen, cenP, 512, 512);
  cn2_kernel<<<512, 256, 0, stream>>>(cen, cn2);

  // ---- encode ----
  encode_kernel<<<NT, 256, 0, stream>>>(x, enc_W, enc_b, resid16);

  // ---- layers ----
  for (int l = 0; l < 2; ++l) {
    ln_kernel<<<NT/4, 256, 0, stream>>>(resid16, h_ln);
    gemm_regb_kernel<false,false><<<dim3(6, 128), 512, 0, stream>>>(
        h_ln, wqP + (size_t)l*786432, qkv, nullptr, NT, 1536, 512);
    attn_kernel<<<4096, 256, 0, stream>>>(qkv, attn_o);
    gemm128_kernel<false,true,0><<<dim3(2, 256), 512, 0, stream>>>(
        attn_o, woP + (size_t)l*262144, resid16, nullptr, resid16, nullptr,
        nullptr, nullptr, nullptr, NT, 512, 512);
    ln_kernel<<<NT/4, 256, 0, stream>>>(resid16, h_ln);
    gemm_regb_kernel<true,true><<<dim3(8, 128), 512, 0, stream>>>(
        h_ln, w1P + (size_t)l*1048576, hidden, b1 + (size_t)l*2048, NT, 2048, 512);
    if (l == 0) {
      gemm128_kernel<true,true,0><<<dim3(2, 256), 512, 0, stream>>>(
          hidden, w2P + (size_t)l*1048576, resid16, b2 + (size_t)l*512, resid16, nullptr,
          nullptr, nullptr, nullptr, NT, 512, 2048);
    } else {
      gemm128_kernel<true,true,3><<<dim3(2, 256), 512, 0, stream>>>(
          hidden, w2P + (size_t)l*1048576, out + 1, b2 + (size_t)l*512, resid16, h_ln,
          nullptr, nullptr, nullptr, NT, 512, 2048);
    }
  }

  // ---- head: fused cdist-argmin + loss ----
  gemm128_kernel<false,false,4><<<dim3(2, 256), 512, 0, stream>>>(
      h_ln, cenP, nullptr, nullptr, nullptr, nullptr,
      cn2, pminv, pmini, NT, 512, 512);
  argmin_kernel<<<NT/4, 256, 0, stream>>>(pminv, pmini, out + 1, cen, partial);
  loss_kernel<<<1, 256, 0, stream>>>(partial, NT/4, out);
}

// Round 21
// 844.786 us; speedup vs baseline: 1.0632x; 1.0632x over previous
//
#include <hip/hip_runtime.h>
#include <cstdint>
#include <cstddef>

typedef __attribute__((ext_vector_type(4))) float f32x4;
typedef __attribute__((ext_vector_type(8))) short s16x8;
typedef __attribute__((ext_vector_type(4))) short s16x4;

__device__ __forceinline__ short f2bf(float f){
  unsigned u; __builtin_memcpy(&u, &f, 4);
  u += 0x7fffu + ((u >> 16) & 1u);
  return (short)(u >> 16);
}
__device__ __forceinline__ float bf2f(short s){
  unsigned u = ((unsigned)(unsigned short)s) << 16;
  float f; __builtin_memcpy(&f, &u, 4);
  return f;
}

__device__ __forceinline__ void gll16(const void* g, void* l) {
  auto* lp = (__attribute__((address_space(3))) unsigned*)(uintptr_t)(l);
  const auto* gp = (const __attribute__((address_space(1))) unsigned*)(uintptr_t)(g);
  __builtin_amdgcn_global_load_lds(gp, lp, 16, 0, 0);
}

__device__ __forceinline__ void ds_tr8(unsigned a, s16x4* r) {
  asm volatile(
    "ds_read_b64_tr_b16 %0, %8\n\t"
    "ds_read_b64_tr_b16 %1, %8 offset:512\n\t"
    "ds_read_b64_tr_b16 %2, %8 offset:2048\n\t"
    "ds_read_b64_tr_b16 %3, %8 offset:2560\n\t"
    "ds_read_b64_tr_b16 %4, %8 offset:4096\n\t"
    "ds_read_b64_tr_b16 %5, %8 offset:4608\n\t"
    "ds_read_b64_tr_b16 %6, %8 offset:6144\n\t"
    "ds_read_b64_tr_b16 %7, %8 offset:6656\n\t"
    "s_waitcnt lgkmcnt(0)"
    : "=&v"(r[0]), "=&v"(r[1]), "=&v"(r[2]), "=&v"(r[3]),
      "=&v"(r[4]), "=&v"(r[5]), "=&v"(r[6]), "=&v"(r[7])
    : "v"(a)
    : "memory");
}

// fragment-major packed index (for B operands of the reg-B GEMM)
__device__ __forceinline__ int pidx(int m, int k, int ntk) {
  return ((m >> 4) * ntk + (k >> 5)) * 512 + ((((k >> 3) & 3) * 16 + (m & 15)) << 3) + (k & 7);
}

// ---------------- encode: -> bf16 resid ----------------
__global__ __launch_bounds__(256) void encode_kernel(
    const float* __restrict__ x, const float* __restrict__ W,
    const float* __restrict__ b, short* __restrict__ out)
{
  const int t = blockIdx.x;
  float xv[8];
#pragma unroll
  for (int f = 0; f < 8; ++f) xv[f] = x[(size_t)t*8 + f];
  for (int d = threadIdx.x; d < 512; d += 256) {
    float acc = b[d];
#pragma unroll
    for (int f = 0; f < 8; ++f) acc += xv[f] * W[f*512 + d];
    out[(size_t)t*512 + d] = f2bf(acc);
  }
}

// ---------------- LayerNorm: bf16 in -> bf16 row-major out ----------------
__global__ __launch_bounds__(256) void ln_kernel(
    const short* __restrict__ x16, short* __restrict__ out)
{
  const int w = threadIdx.x >> 6, lane = threadIdx.x & 63;
  const int t = blockIdx.x * 4 + w;
  s16x8 v = *(const s16x8*)&x16[(size_t)t*512 + lane*8];
  float vals[8];
#pragma unroll
  for (int i = 0; i < 8; ++i) vals[i] = bf2f(v[i]);
  float s = 0.f, sq = 0.f;
#pragma unroll
  for (int i = 0; i < 8; ++i) { s += vals[i]; sq += vals[i]*vals[i]; }
#pragma unroll
  for (int m = 1; m < 64; m <<= 1) { s += __shfl_xor(s, m); sq += __shfl_xor(sq, m); }
  float mean = s * (1.f/512.f);
  float var  = sq * (1.f/512.f) - mean*mean;
  float rstd = rsqrtf(var + 1e-5f);
  s16x8 o;
#pragma unroll
  for (int i = 0; i < 8; ++i) o[i] = f2bf((vals[i]-mean)*rstd);
  *(s16x8*)&out[(size_t)t*512 + lane*8] = o;
}

// ---------------- weight prep ----------------
__global__ __launch_bounds__(256) void transpose_bf16_kernel(
    const float* __restrict__ in, short* __restrict__ out, int K, int N, int kshift)
{
  const int o = blockIdx.x * 256 + threadIdx.x; // o = n*K + k
  const int k = o & (K - 1), n = o >> kshift;
  out[o] = f2bf(in[(size_t)k * N + n]);
}

__global__ __launch_bounds__(256) void convert_bf16_kernel(
    const float* __restrict__ in, short* __restrict__ out)
{
  const int i = blockIdx.x * 256 + threadIdx.x;
  out[i] = f2bf(in[i]);
}

__global__ __launch_bounds__(256) void packB_kernel(
    const float* __restrict__ in, short* __restrict__ out, int K, int N)
{
  const int n = blockIdx.x * 256 + threadIdx.x;
  const int k = blockIdx.y;
  out[pidx(n, k, K >> 5)] = f2bf(in[(size_t)k * N + n]);
}

// ============ GEMM variant 1: phased, A+B in LDS, FREE-RUNNING waves ============
// Same buffers/vmcnt protocol as the verified 8-phase kernel, but the 6
// intra-tile s_barriers (pacing-only; all intra-tile reads hit buf u&1 while
// stages write (u+1)&1/(u+2)&1) are removed so waves slip phase and the CU's
// LDS and MFMA pipes are co-occupied by different waves. One s_barrier +
// counted vmcnt gate per K-tile.
// OUTMODE: 0 = bf16 row-major, 2 = fp32 row-major, 3 = FINAL (fp32 + bf16 obf),
//          4 = fused cdist-argmin
template<bool BIAS, bool RESID16, int OUTMODE>
__global__ __launch_bounds__(512, 1) void gemm_8ph_kernel(
    const short* __restrict__ A, const short* __restrict__ Bt,
    void* Cout, const float* __restrict__ bias,
    const short* __restrict__ resid16, short* __restrict__ obf,
    const float* __restrict__ cn2g, float* __restrict__ pminv,
    int* __restrict__ pmini, int M, int N, int K)
{
  __shared__ short As[2][2][8192];
  __shared__ short Bs[2][2][8192];
  const int tid = threadIdx.x;
  const int lane = tid & 63, w = tid >> 6;
  const int wr = w >> 2, wc = w & 3;
  const int q = lane & 15, gl = lane >> 4;

  const int nx = gridDim.x;
  const int d = blockIdx.y * nx + blockIdx.x;
  const int per = (nx * gridDim.y) >> 3;
  const int lid = (d & 7) * per + (d >> 3);
  const int bx = lid % nx, by = lid / nx;
  const int m0 = by * 256, n0 = bx * 256;

  const int r_lo = tid >> 3, sp = tid & 7;
  const int scol = (sp ^ (r_lo & 7)) * 8;
  const int ldst = tid * 8;

  auto STA = [&](int kt, int h) {
    short* dst = &As[kt & 1][h][ldst];
    const short* s = A + (size_t)(m0 + h*128 + r_lo) * K + (kt << 6) + scol;
    gll16(s, dst);
    gll16(s + (size_t)64 * K, dst + 4096);
  };
  auto STB = [&](int kt, int h) {
    short* dst = &Bs[kt & 1][h][ldst];
    const short* s = Bt + (size_t)(n0 + h*128 + r_lo) * K + (kt << 6) + scol;
    gll16(s, dst);
    gll16(s + (size_t)64 * K, dst + 4096);
  };

  const int x0 = ( gl      ^ (q & 7)) * 8;
  const int x1 = ((gl + 4) ^ (q & 7)) * 8;
  const int aoff = q * 64;
  const int boff = ((wc & 1) * 64 + q) * 64;
  const int bh = wc >> 1;

  f32x4 acc[8][4] = {};
  const int NT = K >> 6;

#define ARD(dst, mi, ks) dst = *(const s16x8*)&Awr[(mi)*1024 + aoff + ((ks) ? x1 : x0)]
#define BRD(dst, ni, ks) dst = *(const s16x8*)&Bh_[(ni)*1024 + boff + ((ks) ? x1 : x0)]
#define MM(mi, ni, af0, af1) \
  acc[mi][ni] = __builtin_amdgcn_mfma_f32_16x16x32_bf16(af0, bF[(ni)*2],   acc[mi][ni], 0, 0, 0); \
  acc[mi][ni] = __builtin_amdgcn_mfma_f32_16x16x32_bf16(af1, bF[(ni)*2+1], acc[mi][ni], 0, 0, 0)
#define SB __builtin_amdgcn_sched_barrier(0);

  STA(0,0); STA(0,1); STB(0,0); STB(0,1);
  STA(1,0); STA(1,1); STB(1,0); STB(1,1);
  asm volatile("s_waitcnt vmcnt(8)" ::: "memory");
  __builtin_amdgcn_sched_barrier(0);
  __builtin_amdgcn_s_barrier();

  for (int u = 0; u < NT; ++u) {
    const short* Awr = &As[u & 1][wr][0];
    const short* Bh_ = &Bs[u & 1][bh][0];
    s16x8 aF[8], bF[8];
    // phase 0: stage A(u+1)h0 | read A(mi0-3) + B(ni0-1) | MFMA q0
    if (u >= 1 && u + 1 < NT) STA(u + 1, 0);
    ARD(aF[0],0,0); ARD(aF[1],0,1); ARD(aF[2],1,0); ARD(aF[3],1,1);
    ARD(aF[4],2,0); ARD(aF[5],2,1); ARD(aF[6],3,0); ARD(aF[7],3,1);
    BRD(bF[0],0,0); BRD(bF[1],0,1); BRD(bF[2],1,0); BRD(bF[3],1,1);
    SB
    __builtin_amdgcn_s_setprio(1);
    MM(0,0,aF[0],aF[1]); MM(1,0,aF[2],aF[3]); MM(2,0,aF[4],aF[5]); MM(3,0,aF[6],aF[7]);
    MM(0,1,aF[0],aF[1]); MM(1,1,aF[2],aF[3]); MM(2,1,aF[4],aF[5]); MM(3,1,aF[6],aF[7]);
    __builtin_amdgcn_s_setprio(0);
    SB
    // phase 1: stage A(u+1)h1 | read B(ni2-3) | MFMA q1
    if (u >= 1 && u + 1 < NT) STA(u + 1, 1);
    BRD(bF[4],2,0); BRD(bF[5],2,1); BRD(bF[6],3,0); BRD(bF[7],3,1);
    SB
    __builtin_amdgcn_s_setprio(1);
    MM(0,2,aF[0],aF[1]); MM(1,2,aF[2],aF[3]); MM(2,2,aF[4],aF[5]); MM(3,2,aF[6],aF[7]);
    MM(0,3,aF[0],aF[1]); MM(1,3,aF[2],aF[3]); MM(2,3,aF[4],aF[5]); MM(3,3,aF[6],aF[7]);
    __builtin_amdgcn_s_setprio(0);
    SB
    // phase 2: stage B(u+2)h0 | read A(mi4-7) | MFMA q2
    if (u + 2 < NT) STB(u + 2, 0);
    ARD(aF[0],4,0); ARD(aF[1],4,1); ARD(aF[2],5,0); ARD(aF[3],5,1);
    ARD(aF[4],6,0); ARD(aF[5],6,1); ARD(aF[6],7,0); ARD(aF[7],7,1);
    SB
    __builtin_amdgcn_s_setprio(1);
    MM(4,0,aF[0],aF[1]); MM(5,0,aF[2],aF[3]); MM(6,0,aF[4],aF[5]); MM(7,0,aF[6],aF[7]);
    MM(4,1,aF[0],aF[1]); MM(5,1,aF[2],aF[3]); MM(6,1,aF[4],aF[5]); MM(7,1,aF[6],aF[7]);
    __builtin_amdgcn_s_setprio(0);
    SB
    // phase 3: stage B(u+2)h1 | MFMA q3 | tile gate
    if (u + 2 < NT) STB(u + 2, 1);
    SB
    __builtin_amdgcn_s_setprio(1);
    MM(4,2,aF[0],aF[1]); MM(5,2,aF[2],aF[3]); MM(6,2,aF[4],aF[5]); MM(7,2,aF[6],aF[7]);
    MM(4,3,aF[0],aF[1]); MM(5,3,aF[2],aF[3]); MM(6,3,aF[4],aF[5]); MM(7,3,aF[6],aF[7]);
    __builtin_amdgcn_s_setprio(0);
    if (u + 1 < NT) {
      if (u + 2 < NT) asm volatile("s_waitcnt vmcnt(4)" ::: "memory");
      else            asm volatile("s_waitcnt vmcnt(0)" ::: "memory");
    }
    __builtin_amdgcn_sched_barrier(0);
    __builtin_amdgcn_s_barrier();
    __builtin_amdgcn_sched_barrier(0);
  }
#undef ARD
#undef BRD
#undef MM
#undef SB

  if (OUTMODE == 4) {
    float c2[4];
#pragma unroll
    for (int ni = 0; ni < 4; ++ni) c2[ni] = cn2g[n0 + wc*64 + ni*16 + q];
    float* redv = (float*)&As[0][0][0];
    int*   redi = (int*)&Bs[0][0][0];
#pragma unroll
    for (int mi = 0; mi < 8; ++mi) {
#pragma unroll
      for (int r = 0; r < 4; ++r) {
        float bv = 1e30f; int bidx = 0;
#pragma unroll
        for (int ni = 0; ni < 4; ++ni) {
          const int ci = n0 + wc*64 + ni*16 + q;
          const float dv = c2[ni] - 2.f * acc[mi][ni][r];
          if (dv < bv || (dv == bv && ci < bidx)) { bv = dv; bidx = ci; }
        }
#pragma unroll
        for (int mm = 1; mm < 16; mm <<= 1) {
          const float ov = __shfl_xor(bv, mm); const int oi = __shfl_xor(bidx, mm);
          if (ov < bv || (ov == bv && oi < bidx)) { bv = ov; bidx = oi; }
        }
        if (q == 0) {
          const int lr = wr*128 + mi*16 + gl*4 + r;
          redv[lr*4 + wc] = bv; redi[lr*4 + wc] = bidx;
        }
      }
    }
    __syncthreads();
    if (tid < 256) {
      float bv = 1e30f; int bidx = 0;
#pragma unroll
      for (int j = 0; j < 4; ++j) {
        const float ov = redv[tid*4 + j]; const int oi = redi[tid*4 + j];
        if (ov < bv || (ov == bv && oi < bidx)) { bv = ov; bidx = oi; }
      }
      pminv[(size_t)(m0 + tid)*2 + bx] = bv;
      pmini[(size_t)(m0 + tid)*2 + bx] = bidx;
    }
  } else {
#pragma unroll
    for (int mi = 0; mi < 8; ++mi) {
#pragma unroll
      for (int r = 0; r < 4; ++r) {
        const int gr = m0 + wr*128 + mi*16 + gl*4 + r;
#pragma unroll
        for (int ni = 0; ni < 4; ++ni) {
          const int gc = n0 + wc*64 + ni*16 + q;
          float v = acc[mi][ni][r];
          if (BIAS) v += bias[gc];
          const size_t idx = (size_t)gr * N + gc;
          if (RESID16) v += bf2f(resid16[idx]);
          if (OUTMODE == 0)      ((short*)Cout)[idx] = f2bf(v);
          else if (OUTMODE == 2) ((float*)Cout)[idx] = v;
          else { ((float*)Cout)[idx] = v; obf[idx] = f2bf(v); }
        }
      }
    }
  }
}

// ============ GEMM variant 2: B in registers ============
template<bool BIAS, bool RELU>
__global__ __launch_bounds__(512, 1) void gemm_regb_kernel(
    const short* __restrict__ A, const short* __restrict__ Bp,
    short* __restrict__ Cout, const float* __restrict__ bias, int M, int N, int K)
{
  __shared__ short As[4][256 * 32];   // 64 KB, A only
  const int tid = threadIdx.x;
  const int lane = tid & 63, w = tid >> 6;
  const int wr = w >> 2, wc = w & 3;
  const int q = lane & 15, g = lane >> 4;

  const int nx = gridDim.x;
  const int d = blockIdx.y * nx + blockIdx.x;
  const int per = (nx * gridDim.y) >> 3;
  const int lid = (d & 7) * per + (d >> 3);
  const int bx = lid % nx, by = lid / nx;
  const int m0 = by * 256, n0 = bx * 256;

  const int srow = lane >> 2;
  const int scol = (((lane & 3) ^ ((lane >> 4) & 3)) * 8);
  const short* aS0 = A + (size_t)(m0 + w*32 + srow) * K + scol;
  const short* aS1 = aS0 + (size_t)16 * K;
  const int d0 = (w*2) * 512, d1 = (w*2 + 1) * 512;
  const int gs = (g ^ (q >> 2)) * 8;

  const int nt = K >> 5;
  const size_t bstep = (size_t)nt * 512;
  const short* bp0 = Bp + ((size_t)(n0 >> 4) + wc * 4) * bstep + lane * 8;

  f32x4 acc[8][4] = {};

  auto STAGE_A = [&](int tt) {
    const int k0 = tt << 5, nb = tt & 3;
    gll16(aS0 + k0, &As[nb][d0]);
    gll16(aS1 + k0, &As[nb][d1]);
  };
  s16x8 bA[4], bB[4];
  auto LOADB = [&](int tt, s16x8* bf) {
#pragma unroll
    for (int i = 0; i < 4; ++i)
      bf[i] = *(const s16x8*)&bp0[(size_t)i * bstep + (size_t)tt * 512];
  };
  auto TILE = [&](int t, s16x8* bcur, s16x8* bnxt, bool doLB, bool doSA) {
    __builtin_amdgcn_s_barrier();
    __builtin_amdgcn_sched_barrier(0);
    if (doLB) LOADB(t + 1, bnxt);
    __builtin_amdgcn_sched_barrier(0);
    if (doSA) STAGE_A(t + 3);
    __builtin_amdgcn_sched_barrier(0);
    const short* Ab = &As[t & 3][0];
    s16x8 aF[8];
#pragma unroll
    for (int i = 0; i < 8; ++i) aF[i] = *(const s16x8*)&Ab[(wr*128 + i*16 + q)*32 + gs];
    __builtin_amdgcn_s_setprio(1);
#pragma unroll
    for (int mi = 0; mi < 8; ++mi)
#pragma unroll
      for (int ni = 0; ni < 4; ++ni)
        acc[mi][ni] = __builtin_amdgcn_mfma_f32_16x16x32_bf16(aF[mi], bcur[ni], acc[mi][ni], 0, 0, 0);
    __builtin_amdgcn_s_setprio(0);
  };

  STAGE_A(0);
  LOADB(0, bA);
  STAGE_A(1);
  STAGE_A(2);

  for (int t = 0; t < nt - 2; t += 2) {
    asm volatile("s_waitcnt vmcnt(8)" ::: "memory");
    TILE(t, bA, bB, true, true);
    asm volatile("s_waitcnt vmcnt(8)" ::: "memory");
    TILE(t + 1, bB, bA, true, t + 4 < nt);
  }
  asm volatile("s_waitcnt vmcnt(6)" ::: "memory");
  TILE(nt - 2, bA, bB, true, false);
  asm volatile("s_waitcnt vmcnt(4)" ::: "memory");
  TILE(nt - 1, bB, bA, false, false);

#pragma unroll
  for (int mi = 0; mi < 8; ++mi) {
#pragma unroll
    for (int r = 0; r < 4; ++r) {
      const int gr = m0 + wr*128 + mi*16 + g*4 + r;
#pragma unroll
      for (int ni = 0; ni < 4; ++ni) {
        const int gc = n0 + wc*64 + ni*16 + q;
        float v = acc[mi][ni][r];
        if (BIAS) v += bias[gc];
        if (RELU) v = fmaxf(v, 0.f);
        Cout[(size_t)gr * N + gc] = f2bf(v);
      }
    }
  }
}

// ---------------- flash attention ----------------
__global__ __launch_bounds__(256) void attn_kernel(
    const short* __restrict__ qkv, short* __restrict__ attn_out)
{
  __shared__ short Ks[2][64 * 64];
  __shared__ short Vs[2][64 * 64];
  const int tid = threadIdx.x;
  const int w = tid >> 6, lane = tid & 63;
  const int q16 = lane & 15, g = lane >> 4;
  const int dd = blockIdx.x;
  const int lid = (dd & 7) * (int)(gridDim.x >> 3) + (dd >> 3);
  const int qt4 = lid & 7, h = (lid >> 3) & 7, b = lid >> 6;
  const size_t base = (size_t)b * 512 * 1536;
  const int qrow = qt4*64 + w*16 + q16;

  s16x8 bQ0, bQ1;
  {
    const size_t p = base + (size_t)qrow * 1536 + h*64 + g*8;
    bQ0 = *(const s16x8*)&qkv[p];
    bQ1 = *(const s16x8*)&qkv[p + 32];
  }

  const int c0 = w*2, c1 = w*2 + 1;
  const short* kS0 = qkv + base + (size_t)(c0*8 + (lane>>3))*1536 + 512 + h*64 + ((lane&7)^(lane>>3))*8;
  const short* kS1 = qkv + base + (size_t)(c1*8 + (lane>>3))*1536 + 512 + h*64 + ((lane&7)^(lane>>3))*8;
  const short* vS0 = qkv + base + (size_t)((c0&1)*32 + (lane>>1))*1536 + 1024 + h*64 + (c0>>1)*16 + (lane&1)*8;
  const short* vS1 = qkv + base + (size_t)((c1&1)*32 + (lane>>1))*1536 + 1024 + h*64 + (c1>>1)*16 + (lane&1)*8;

  const unsigned vs_lane = (unsigned)(size_t)(&Vs[0][0]) + (unsigned)((q16 + g*64)*2);
  const int sw = q16 & 7;

  float mrun = -1e30f, ssum = 0.f;
  f32x4 O[4] = {};

  gll16(kS0, &Ks[0][c0*512]);
  gll16(kS1, &Ks[0][c1*512]);
  gll16(vS0, &Vs[0][c0*512]);
  gll16(vS1, &Vs[0][c1*512]);
  __syncthreads();

  int cur = 0;
  for (int j0 = 0; j0 < 512; j0 += 64) {
    s16x8 ka0[4], ka1[4];
#pragma unroll
    for (int grp = 0; grp < 4; ++grp) {
      const int rb = (grp*16 + q16) * 64;
      ka0[grp] = *(const s16x8*)&Ks[cur][rb + ((g    ) ^ sw)*8];
      ka1[grp] = *(const s16x8*)&Ks[cur][rb + ((g + 4) ^ sw)*8];
    }
    if (j0 + 64 < 512) {
      const size_t joff = (size_t)(j0 + 64) * 1536;
      const int nxt = cur ^ 1;
      gll16(kS0 + joff, &Ks[nxt][c0*512]);
      gll16(kS1 + joff, &Ks[nxt][c1*512]);
      gll16(vS0 + joff, &Vs[nxt][c0*512]);
      gll16(vS1 + joff, &Vs[nxt][c1*512]);
    }
    __builtin_amdgcn_sched_barrier(0);

    f32x4 c[4];
    __builtin_amdgcn_s_setprio(1);
#pragma unroll
    for (int grp = 0; grp < 4; ++grp) {
      f32x4 z = {};
      c[grp] = __builtin_amdgcn_mfma_f32_16x16x32_bf16(ka0[grp], bQ0, z, 0, 0, 0);
      c[grp] = __builtin_amdgcn_mfma_f32_16x16x32_bf16(ka1[grp], bQ1, c[grp], 0, 0, 0);
    }
    __builtin_amdgcn_s_setprio(0);

    float sc[16];
#pragma unroll
    for (int grp = 0; grp < 4; ++grp)
#pragma unroll
      for (int r = 0; r < 4; ++r) sc[grp*4 + r] = c[grp][r] * 0.125f;
    float bm = sc[0];
#pragma unroll
    for (int i = 1; i < 16; ++i) bm = fmaxf(bm, sc[i]);
    bm = fmaxf(bm, __shfl_xor(bm, 16));
    bm = fmaxf(bm, __shfl_xor(bm, 32));
    const float mn = fmaxf(mrun, bm);
    const float alpha = __expf(mrun - mn);
    float p[16]; float bs = 0.f;
#pragma unroll
    for (int i = 0; i < 16; ++i) { p[i] = __expf(sc[i] - mn); bs += p[i]; }
    bs += __shfl_xor(bs, 16);
    bs += __shfl_xor(bs, 32);
    ssum = ssum * alpha + bs;
    mrun = mn;
#pragma unroll
    for (int db = 0; db < 4; ++db) O[db] *= alpha;

#pragma unroll
    for (int kk = 0; kk < 2; ++kk) {
      s16x8 pf;
#pragma unroll
      for (int e = 0; e < 8; ++e) pf[e] = f2bf(p[(kk*2 + (e >> 2))*4 + (e & 3)]);
      s16x4 r[8];
      ds_tr8(vs_lane + (unsigned)(cur << 13) + (unsigned)(kk*1024), r);
      __builtin_amdgcn_sched_barrier(0);
      __builtin_amdgcn_s_setprio(1);
#pragma unroll
      for (int db = 0; db < 4; ++db) {
        s16x8 vf = __builtin_shufflevector(r[2*db], r[2*db + 1], 0, 1, 2, 3, 4, 5, 6, 7);
        O[db] = __builtin_amdgcn_mfma_f32_16x16x32_bf16(vf, pf, O[db], 0, 0, 0);
      }
      __builtin_amdgcn_s_setprio(0);
    }
    __syncthreads();
    cur ^= 1;
  }

  const float inv = 1.f / ssum;
  const size_t tok = (size_t)b*512 + qrow;
#pragma unroll
  for (int db = 0; db < 4; ++db) {
    s16x4 ov;
#pragma unroll
    for (int r = 0; r < 4; ++r) ov[r] = f2bf(O[db][r] * inv);
    *(s16x4*)&attn_out[tok*512 + h*64 + db*16 + g*4] = ov;
  }
}

// ---------------- cn2 ----------------
__global__ __launch_bounds__(256) void cn2_kernel(
    const float* __restrict__ centers, float* __restrict__ cn2)
{
  const int c = blockIdx.x;
  __shared__ float red[256];
  float s = 0.f;
  for (int d = threadIdx.x; d < 512; d += 256) { float v = centers[(size_t)c*512 + d]; s += v*v; }
  red[threadIdx.x] = s; __syncthreads();
  for (int off = 128; off > 0; off >>= 1) {
    if (threadIdx.x < off) red[threadIdx.x] += red[threadIdx.x + off];
    __syncthreads();
  }
  if (threadIdx.x == 0) cn2[c] = red[0];
}

// ---------------- winner pick + loss partials ----------------
__global__ __launch_bounds__(256) void argmin_kernel(
    const float* __restrict__ pminv, const int* __restrict__ pmini,
    const float* __restrict__ seq, const float* __restrict__ centers,
    float* __restrict__ partial)
{
  const int w = threadIdx.x >> 6, lane = threadIdx.x & 63;
  const int t = blockIdx.x * 4 + w;
  const float d0 = pminv[(size_t)t*2], d1 = pminv[(size_t)t*2 + 1];
  const int   i0 = pmini[(size_t)t*2], i1 = pmini[(size_t)t*2 + 1];
  const int bi = (d1 < d0) ? i1 : i0;
  float s = 0.f;
#pragma unroll
  for (int j = 0; j < 8; ++j) {
    const int dcol = j*64 + lane;
    const float o = seq[(size_t)t*512 + dcol];
    const float c = centers[(size_t)bi*512 + dcol];
    const float dv = o - c;
    s += dv * dv;
  }
#pragma unroll
  for (int mm = 1; mm < 64; mm <<= 1) s += __shfl_xor(s, mm);
  __shared__ float red[4];
  if (lane == 0) red[w] = s;
  __syncthreads();
  if (threadIdx.x == 0) partial[blockIdx.x] = red[0] + red[1] + red[2] + red[3];
}

__global__ __launch_bounds__(256) void loss_kernel(
    const float* __restrict__ partial, int n, float* __restrict__ out)
{
  float s = 0.f;
  for (int i = threadIdx.x; i < n; i += 256) s += partial[i];
  __shared__ float red[256];
  red[threadIdx.x] = s; __syncthreads();
  for (int off = 128; off > 0; off >>= 1) {
    if (threadIdx.x < off) red[threadIdx.x] += red[threadIdx.x + off];
    __syncthreads();
  }
  if (threadIdx.x == 0) out[0] = red[0] * (1.f / 32768.f);
}

// ==========================================================================
extern "C" void kernel_launch(void* const* d_in, const int* in_sizes, int n_in,
                              void* d_out, int out_size, void* d_ws, size_t ws_size,
                              hipStream_t stream) {
  const float* x     = (const float*)d_in[0];
  const float* enc_W = (const float*)d_in[1];
  const float* enc_b = (const float*)d_in[2];
  const float* Wqkv  = (const float*)d_in[3];
  const float* Wo    = (const float*)d_in[4];
  const float* W1    = (const float*)d_in[5];
  const float* b1    = (const float*)d_in[6];
  const float* W2    = (const float*)d_in[7];
  const float* b2    = (const float*)d_in[8];
  const float* cen   = (const float*)d_in[9];
  float* out = (float*)d_out;

  const int NT = 32768;           // B*S tokens
  char* ws = (char*)d_ws;
  short* resid16 = (short*)(ws);                                  // 32 MB bf16 resid
  short* h_ln    = (short*)(ws + 67108864);                       // 32 MB row-major
  char*  pool    = ws + 100663296;                                // 128 MB shared pool
  short* qkv     = (short*)pool;                                  // 96 MB row-major
  short* attn_o  = (short*)(pool + 100663296);                    // 32 MB row-major
  short* hidden  = (short*)pool;                                  // 128 MB row-major (after attn)
  float* pminv   = (float*)pool;                                  // 256 KB (after hidden dead)
  int*   pmini   = (int*)(pool + 262144);                         // 256 KB
  short* wbase   = (short*)(ws + 234881024);                      // weights
  short* wqP     = wbase;                                         // packed, 2 x 786432
  short* woT     = wbase + 1572864;                                // transposed, 2 x 262144
  short* w1P     = wbase + 2097152;                                // packed, 2 x 1048576
  short* w2T     = wbase + 4194304;                                // transposed, 2 x 1048576
  short* cenb    = wbase + 6291456;                                // [cluster][d] bf16
  float* cn2     = (float*)(ws + 247988224);
  float* partial = (float*)(ws + 247990272);

  // ---- weight prep ----
  for (int l = 0; l < 2; ++l) {
    packB_kernel<<<dim3(6, 512), 256, 0, stream>>>(Wqkv + (size_t)l*512*1536, wqP + (size_t)l*786432, 512, 1536);
    transpose_bf16_kernel<<<1024, 256, 0, stream>>>(Wo  + (size_t)l*512*512,  woT + (size_t)l*262144, 512, 512, 9);
    packB_kernel<<<dim3(8, 512), 256, 0, stream>>>(W1   + (size_t)l*512*2048, w1P + (size_t)l*1048576, 512, 2048);
    transpose_bf16_kernel<<<4096, 256, 0, stream>>>(W2  + (size_t)l*2048*512, w2T + (size_t)l*1048576, 2048, 512, 11);
  }
  convert_bf16_kernel<<<1024, 256, 0, stream>>>(cen, cenb);
  cn2_kernel<<<512, 256, 0, stream>>>(cen, cn2);

  // ---- encode ----
  encode_kernel<<<NT, 256, 0, stream>>>(x, enc_W, enc_b, resid16);

  // ---- layers ----
  for (int l = 0; l < 2; ++l) {
    ln_kernel<<<NT/4, 256, 0, stream>>>(resid16, h_ln);
    gemm_regb_kernel<false,false><<<dim3(6, 128), 512, 0, stream>>>(
        h_ln, wqP + (size_t)l*786432, qkv, nullptr, NT, 1536, 512);
    attn_kernel<<<4096, 256, 0, stream>>>(qkv, attn_o);
    gemm_8ph_kernel<false,true,0><<<dim3(2, 128), 512, 0, stream>>>(
        attn_o, woT + (size_t)l*262144, resid16, nullptr, resid16, nullptr,
        nullptr, nullptr, nullptr, NT, 512, 512);
    ln_kernel<<<NT/4, 256, 0, stream>>>(resid16, h_ln);
    gemm_regb_kernel<true,true><<<dim3(8, 128), 512, 0, stream>>>(
        h_ln, w1P + (size_t)l*1048576, hidden, b1 + (size_t)l*2048, NT, 2048, 512);
    if (l == 0) {
      gemm_8ph_kernel<true,true,0><<<dim3(2, 128), 512, 0, stream>>>(
          hidden, w2T + (size_t)l*1048576, resid16, b2 + (size_t)l*512, resid16, nullptr,
          nullptr, nullptr, nullptr, NT, 512, 2048);
    } else {
      gemm_8ph_kernel<true,true,3><<<dim3(2, 128), 512, 0, stream>>>(
          hidden, w2T + (size_t)l*1048576, out + 1, b2 + (size_t)l*512, resid16, h_ln,
          nullptr, nullptr, nullptr, NT, 512, 2048);
    }
  }

  // ---- head: fused cdist-argmin + loss ----
  gemm_8ph_kernel<false,false,4><<<dim3(2, 128), 512, 0, stream>>>(
      h_ln, cenb, nullptr, nullptr, nullptr, nullptr,
      cn2, pminv, pmini, NT, 512, 512);
  argmin_kernel<<<NT/4, 256, 0, stream>>>(pminv, pmini, out + 1, cen, partial);
  loss_kernel<<<1, 256, 0, stream>>>(partial, NT/4, out);
}